// Round 1
// baseline (820.211 us; speedup 1.0000x reference)
//
#include <hip/hip_runtime.h>

typedef __attribute__((ext_vector_type(4))) float f32x4;
typedef __attribute__((ext_vector_type(8))) short bf16x8;

#define BATCH 8
#define MDIM 4096
#define KDIM 4096
#define NDIM 128
#define BM 64
#define BK 128
#define NT 32      // KDIM / BK
#define BLOCK 256

__device__ __forceinline__ ushort f2bf(float f) {
  unsigned u = __float_as_uint(f);
  unsigned r = (u + 0x7fffu + ((u >> 16) & 1u)) >> 16;  // RNE
  return (ushort)r;
}

// ---------------- pre-kernel: B [b][k][n] fp32 -> Bt [b][n][k] bf16 ----------------
__global__ __launch_bounds__(256) void conv_b(const float* __restrict__ b,
                                              ushort* __restrict__ bt) {
  int t = blockIdx.x * 256 + threadIdx.x;   // 0 .. 8*128*512-1
  int n  = t & (NDIM - 1);
  int k8 = (t >> 7) & 511;
  int bb = t >> 16;
  int k = k8 * 8;
  const float* src = b + ((size_t)bb * KDIM + k) * NDIM + n;  // b[bb][k][n]
  ushort r[8];
#pragma unroll
  for (int j = 0; j < 8; ++j) r[j] = f2bf(src[(size_t)j * NDIM]);
  ushort* dst = bt + ((size_t)bb * NDIM + n) * KDIM + k;
  *reinterpret_cast<uint4*>(dst) = *reinterpret_cast<const uint4*>(r);
}

// ---------------- main kernel ----------------
__global__ __launch_bounds__(BLOCK, 2) void sparse_bmm(
    const float* __restrict__ a, const ushort* __restrict__ bt,
    float* __restrict__ c) {
  __shared__ ushort As[BM * BK];     // [row][k], XOR-swizzled 16B slots
  __shared__ ushort Bs[NDIM * BK];   // [n][k],  XOR-swizzled 16B slots
  __shared__ int flags[NT];

  const int tid = threadIdx.x;
  const int bb = blockIdx.x & 7;          // batch -> XCD affinity
  const int mt = blockIdx.x >> 3;
  const int lane = tid & 63;
  const int wm = (tid >> 7) & 1;          // wave row (0..1)
  const int wn = (tid >> 6) & 1;          // wave col (0..1)

  if (tid < NT) flags[tid] = 0;

  const float* abase = a + ((size_t)(bb * MDIM + mt * BM)) * KDIM;
  const ushort* bbase = bt + (size_t)bb * NDIM * KDIM;

  f32x4 acc[2][4];
#pragma unroll
  for (int i = 0; i < 2; ++i)
#pragma unroll
    for (int j = 0; j < 4; ++j)
#pragma unroll
      for (int e = 0; e < 4; ++e) acc[i][j][e] = 0.f;

  float4 ra0[8], ra1[8];
  uint4  rb0[8], rb1[8];

  auto load = [&](float4 (&ra)[8], uint4 (&rb)[8], int kt) {
    const float* ap = abase + kt * BK;
    const ushort* bp = bbase + kt * BK;
#pragma unroll
    for (int i = 0; i < 8; ++i) {
      int u = tid + i * BLOCK;                    // A: row=u>>5, float4 q=u&31
      ra[i] = *reinterpret_cast<const float4*>(ap + (size_t)(u >> 5) * KDIM + (u & 31) * 4);
    }
#pragma unroll
    for (int i = 0; i < 8; ++i) {
      int u = tid + i * BLOCK;                    // B: n=u>>4, slot=u&15
      rb[i] = *reinterpret_cast<const uint4*>(bp + (size_t)(u >> 4) * KDIM + (u & 15) * 8);
    }
  };

  auto stage = [&](float4 (&ra)[8], uint4 (&rb)[8], int kt) {
    unsigned nz = 0;
#pragma unroll
    for (int i = 0; i < 8; ++i) {
      int u = tid + i * BLOCK;
      int row = u >> 5, q = u & 31, s = q >> 1, half = q & 1;
      float4 v = ra[i];
      nz |= (__float_as_uint(v.x) | __float_as_uint(v.y) |
             __float_as_uint(v.z) | __float_as_uint(v.w));
      ushort4 h;
      h.x = f2bf(v.x); h.y = f2bf(v.y); h.z = f2bf(v.z); h.w = f2bf(v.w);
      int off = row * 256 + ((s ^ (row & 7)) * 16) + half * 8;
      *reinterpret_cast<ushort4*>(reinterpret_cast<char*>(As) + off) = h;
    }
#pragma unroll
    for (int i = 0; i < 8; ++i) {
      int u = tid + i * BLOCK;
      int n = u >> 4, s = u & 15;
      int off = n * 256 + ((s ^ (n & 7)) * 16);
      *reinterpret_cast<uint4*>(reinterpret_cast<char*>(Bs) + off) = rb[i];
    }
    nz &= 0x7fffffffu;                 // drop sign bit: -0.0 counts as zero
    if (nz) flags[kt] = 1;
  };

  auto compute = [&](int kt) {
    if (flags[kt] == 0) return;        // whole 64x128 A sub-tile is zero
#pragma unroll
    for (int kk = 0; kk < 4; ++kk) {
      bf16x8 af[2], bfr[4];
      int sl = kk * 4 + (lane >> 4);
#pragma unroll
      for (int mi = 0; mi < 2; ++mi) {
        int r = wm * 32 + mi * 16 + (lane & 15);
        int off = r * 256 + ((sl ^ (r & 7)) * 16);
        af[mi] = *reinterpret_cast<const bf16x8*>(reinterpret_cast<const char*>(As) + off);
      }
#pragma unroll
      for (int ni = 0; ni < 4; ++ni) {
        int n = wn * 64 + ni * 16 + (lane & 15);
        int off = n * 256 + ((sl ^ (n & 7)) * 16);
        bfr[ni] = *reinterpret_cast<const bf16x8*>(reinterpret_cast<const char*>(Bs) + off);
      }
#pragma unroll
      for (int mi = 0; mi < 2; ++mi)
#pragma unroll
        for (int ni = 0; ni < 4; ++ni)
          acc[mi][ni] = __builtin_amdgcn_mfma_f32_16x16x32_bf16(
              af[mi], bfr[ni], acc[mi][ni], 0, 0, 0);
    }
  };

  load(ra0, rb0, 0);
  __syncthreads();                      // flags zeroing visible
  for (int kt = 0; kt < NT; kt += 2) {
    load(ra1, rb1, kt + 1);             // prefetch next tile into regs
    stage(ra0, rb0, kt);
    __syncthreads();
    compute(kt);
    __syncthreads();
    if (kt + 2 < NT) load(ra0, rb0, kt + 2);
    stage(ra1, rb1, kt + 1);
    __syncthreads();
    compute(kt + 1);
    __syncthreads();
  }

  // epilogue: D frag mapping col = lane&15, row = (lane>>4)*4 + j  [m89-verified]
  float* cbase = c + ((size_t)(bb * MDIM + mt * BM)) * NDIM;
#pragma unroll
  for (int mi = 0; mi < 2; ++mi)
#pragma unroll
    for (int ni = 0; ni < 4; ++ni)
#pragma unroll
      for (int j = 0; j < 4; ++j) {
        int m = wm * 32 + mi * 16 + (lane >> 4) * 4 + j;
        int n = wn * 64 + ni * 16 + (lane & 15);
        cbase[(size_t)m * NDIM + n] = acc[mi][ni][j];
      }
}

extern "C" void kernel_launch(void* const* d_in, const int* in_sizes, int n_in,
                              void* d_out, int out_size, void* d_ws, size_t ws_size,
                              hipStream_t stream) {
  const float* a = (const float*)d_in[0];   // [8][4096][4096] fp32
  const float* b = (const float*)d_in[1];   // [8][4096][128]  fp32
  float* out = (float*)d_out;               // [8][4096][128]  fp32
  ushort* bt = (ushort*)d_ws;               // [8][128][4096]  bf16 (8.4 MB)

  conv_b<<<2048, 256, 0, stream>>>(b, bt);
  sparse_bmm<<<BATCH * (MDIM / BM), BLOCK, 0, stream>>>(a, bt, out);
}

// Round 2
// 777.027 us; speedup vs baseline: 1.0556x; 1.0556x over previous
//
#include <hip/hip_runtime.h>

typedef __attribute__((ext_vector_type(4))) float f32x4;
typedef __attribute__((ext_vector_type(8))) short bf16x8;

#define BATCH 8
#define MDIM 4096
#define KDIM 4096
#define NDIM 128
#define NT 32      // K tiles of 128
#define BLOCK 256

__device__ __forceinline__ ushort f2bf(float f) {
  unsigned u = __float_as_uint(f);
  unsigned r = (u + 0x7fffu + ((u >> 16) & 1u)) >> 16;  // RNE
  return (ushort)r;
}

// ---------------- pre-kernel: B [b][k][n] fp32 -> Bt [b][n][k] bf16 ----------------
__global__ __launch_bounds__(256) void conv_b(const float* __restrict__ b,
                                              ushort* __restrict__ bt) {
  int t = blockIdx.x * 256 + threadIdx.x;   // 0 .. 8*128*512-1
  int n  = t & (NDIM - 1);
  int k8 = (t >> 7) & 511;
  int bb = t >> 16;
  int k = k8 * 8;
  const float* src = b + ((size_t)bb * KDIM + k) * NDIM + n;  // b[bb][k][n]
  ushort r[8];
#pragma unroll
  for (int j = 0; j < 8; ++j) r[j] = f2bf(src[(size_t)j * NDIM]);
  ushort* dst = bt + ((size_t)bb * NDIM + n) * KDIM + k;
  *reinterpret_cast<uint4*>(dst) = *reinterpret_cast<const uint4*>(r);
}

// ---------------- main kernel: barrier-free, per-wave 16x128 strip ----------------
__global__ __launch_bounds__(BLOCK, 2) void sparse_bmm(
    const float* __restrict__ a, const ushort* __restrict__ bt,
    float* __restrict__ c) {
  const int tid  = threadIdx.x;
  const int lane = tid & 63;
  const int wave = tid >> 6;              // 0..3
  const int bb = blockIdx.x & 7;          // batch -> XCD affinity (Bt slice L2-pinned)
  const int mt = blockIdx.x >> 3;         // 0..63
  const int m0 = mt * 64 + wave * 16;     // wave's 16-row strip

  const int lr = lane & 15;   // A row-in-16 / B col-in-16 / C col-in-16
  const int lk = lane >> 4;   // k-group 0..3 (8 elems each)

  // lane-fixed base pointers: fragment elements are 8 contiguous along k
  const float*  arow = a  + ((size_t)(bb * MDIM + m0 + lr)) * KDIM + lk * 8;
  const ushort* brow = bt + ((size_t)(bb * NDIM + lr)) * KDIM + lk * 8;

  f32x4 acc[8];
#pragma unroll
  for (int ni = 0; ni < 8; ++ni)
#pragma unroll
    for (int e = 0; e < 4; ++e) acc[ni][e] = 0.f;

  float4 ra0[8], ra1[8];      // statically-named double buffers (rule #20)

  auto loadA = [&](float4 (&ra)[8], int kt) {
    const float* p = arow + kt * 128;
#pragma unroll
    for (int kk = 0; kk < 4; ++kk) {
      ra[kk * 2]     = *reinterpret_cast<const float4*>(p + kk * 32);
      ra[kk * 2 + 1] = *reinterpret_cast<const float4*>(p + kk * 32 + 4);
    }
  };

  auto process = [&](float4 (&ra)[8], int kt) {
    unsigned nz = 0;
#pragma unroll
    for (int i = 0; i < 8; ++i)
      nz |= __float_as_uint(ra[i].x) | __float_as_uint(ra[i].y) |
            __float_as_uint(ra[i].z) | __float_as_uint(ra[i].w);
    nz &= 0x7fffffffu;                    // -0.0 counts as zero
    if (!__any((int)(nz != 0u))) return;  // whole 16x128 wave-tile zero -> skip

    bf16x8 af[4];
#pragma unroll
    for (int kk = 0; kk < 4; ++kk) {
      float4 v0 = ra[kk * 2], v1 = ra[kk * 2 + 1];
      ushort h[8];
      h[0] = f2bf(v0.x); h[1] = f2bf(v0.y); h[2] = f2bf(v0.z); h[3] = f2bf(v0.w);
      h[4] = f2bf(v1.x); h[5] = f2bf(v1.y); h[6] = f2bf(v1.z); h[7] = f2bf(v1.w);
      af[kk] = *reinterpret_cast<bf16x8*>(h);
    }

    const ushort* bp = brow + kt * 128;
#pragma unroll
    for (int kk = 0; kk < 4; ++kk) {
      bf16x8 bf[8];
#pragma unroll
      for (int ni = 0; ni < 8; ++ni)
        bf[ni] = *reinterpret_cast<const bf16x8*>(bp + (size_t)ni * 16 * KDIM + kk * 32);
#pragma unroll
      for (int ni = 0; ni < 8; ++ni)
        acc[ni] = __builtin_amdgcn_mfma_f32_16x16x32_bf16(af[kk], bf[ni], acc[ni], 0, 0, 0);
    }
  };

  // 2-deep software pipeline, no barriers anywhere -> prefetch never drained
  loadA(ra0, 0);
  loadA(ra1, 1);
  for (int kt = 0; kt < NT - 2; kt += 2) {
    process(ra0, kt);
    loadA(ra0, kt + 2);
    process(ra1, kt + 1);
    loadA(ra1, kt + 3);
  }
  process(ra0, NT - 2);
  process(ra1, NT - 1);

  // epilogue: C frag mapping col = lane&15, row = (lane>>4)*4 + j  [m89-verified]
  float* crow = c + ((size_t)(bb * MDIM + m0)) * NDIM;
#pragma unroll
  for (int ni = 0; ni < 8; ++ni)
#pragma unroll
    for (int j = 0; j < 4; ++j) {
      int m = lk * 4 + j;
      int n = ni * 16 + lr;
      crow[(size_t)m * NDIM + n] = acc[ni][j];
    }
}

extern "C" void kernel_launch(void* const* d_in, const int* in_sizes, int n_in,
                              void* d_out, int out_size, void* d_ws, size_t ws_size,
                              hipStream_t stream) {
  const float* a = (const float*)d_in[0];   // [8][4096][4096] fp32
  const float* b = (const float*)d_in[1];   // [8][4096][128]  fp32
  float* out = (float*)d_out;               // [8][4096][128]  fp32
  ushort* bt = (ushort*)d_ws;               // [8][128][4096]  bf16 (8.4 MB)

  conv_b<<<2048, 256, 0, stream>>>(b, bt);
  sparse_bmm<<<BATCH * (MDIM / 64), BLOCK, 0, stream>>>(a, bt, out);
}